// Round 1
// baseline (1029.304 us; speedup 1.0000x reference)
//
#include <hip/hip_runtime.h>
#include <cmath>

#define NN   1000
#define TT   4
#define PP   10
#define DD   13
#define FF   128
#define HH   128
#define EAA  16
#define KDIM 64
#define EE   20000
#define I_NODE 91
#define I_EDGE 169
#define MROW  13000   // N*D

// ---------------- K1: m = node_feats @ W_msg ; zero agg ----------------
__global__ __launch_bounds__(128) void k_node_msg(
    const float* __restrict__ nf, const float* __restrict__ Wmsg,
    float* __restrict__ m, float* __restrict__ agg) {
  int n = blockIdx.x, j = threadIdx.x;
  __shared__ float row[FF];
  row[j] = nf[n * FF + j];
  __syncthreads();
  float acc = 0.f;
#pragma unroll 8
  for (int f = 0; f < FF; ++f) acc += row[f] * Wmsg[f * FF + j];
  m[n * FF + j] = acc;
  agg[n * FF + j] = 0.f;
}

// ---------------- K2: symmetric segment sum via atomics ----------------
__global__ __launch_bounds__(256) void k_scatter(
    const float* __restrict__ m, const int* __restrict__ src,
    const int* __restrict__ dst, float* __restrict__ agg) {
  int idx = blockIdx.x * 256 + threadIdx.x;
  if (idx >= EE * FF) return;
  int e = idx >> 7, j = idx & 127;
  int s = src[e], d = dst[e];
  atomicAdd(&agg[d * FF + j], m[s * FF + j]);
  atomicAdd(&agg[s * FF + j], m[d * FF + j]);
}

// ---------------- K3: node_h ----------------
__global__ __launch_bounds__(128) void k_node_h(
    const float* __restrict__ nf, const float* __restrict__ agg,
    const float* __restrict__ na, const float* __restrict__ Wattr,
    float* __restrict__ nh) {
  int n = blockIdx.x, j = threadIdx.x;
  float a = 0.f;
#pragma unroll
  for (int t = 0; t < TT; ++t) a += na[n * TT + t] * Wattr[t * FF + j];
  nh[n * FF + j] = nf[n * FF + j] + agg[n * FF + j] * (1.0f / 20.0f) + a;
}

// ---------------- K4: edge_msg = tanh(e_in @ W_em), 8 edges/block ----------------
#define EPB 8
__global__ __launch_bounds__(128) void k_edge_msg(
    const float* __restrict__ nh, const float* __restrict__ ef,
    const float* __restrict__ ea, const int* __restrict__ src,
    const int* __restrict__ dst, const float* __restrict__ Wem,
    float* __restrict__ emsg) {
  int e0 = blockIdx.x * EPB;
  int j = threadIdx.x;
  __shared__ float xin[EPB][2 * FF + 2 * EAA];  // [8][288]
  for (int e = 0; e < EPB; ++e) {
    int ee = e0 + e;
    int s = src[ee], d = dst[ee];
    for (int i = j; i < 288; i += 128) {
      float v;
      if (i < 128)      v = nh[s * FF + i];
      else if (i < 256) v = nh[d * FF + (i - 128)];
      else if (i < 272) v = ef[ee * EAA + (i - 256)];
      else              v = ea[ee * EAA + (i - 272)];
      xin[e][i] = v;
    }
  }
  __syncthreads();
  float acc[EPB];
#pragma unroll
  for (int e = 0; e < EPB; ++e) acc[e] = 0.f;
  for (int i = 0; i < 288; ++i) {
    float w = Wem[i * HH + j];
#pragma unroll
    for (int e = 0; e < EPB; ++e) acc[e] += xin[e][i] * w;
  }
#pragma unroll
  for (int e = 0; e < EPB; ++e) emsg[(e0 + e) * HH + j] = tanhf(acc[e]);
}

// ---------------- K5: node diagonal blocks ----------------
__global__ __launch_bounds__(256) void k_node_block(
    const float* __restrict__ nh, const int* __restrict__ ntype,
    const float* __restrict__ Wnode, const float* __restrict__ cob,
    float* __restrict__ M) {
  int n = blockIdx.x, t = threadIdx.x;
  int ty = ntype[n];
  __shared__ float row[FF];
  __shared__ float irr[I_NODE];
  if (t < FF) row[t] = nh[n * FF + t];
  __syncthreads();
  if (t < I_NODE) {
    float acc = 0.f;
    const float* W = Wnode + ty * FF * I_NODE + t;
#pragma unroll 4
    for (int f = 0; f < FF; ++f) acc += row[f] * W[f * I_NODE];
    irr[t] = acc;
  }
  __syncthreads();
  if (t < I_EDGE) {
    float acc = 0.f;
    const float* C = cob + ty * I_NODE * I_EDGE + t;
    for (int i = 0; i < I_NODE; ++i) acc += irr[i] * C[i * I_EDGE];
    int x = t / DD, y = t % DD;
    atomicAdd(&M[(size_t)(n * DD + x) * MROW + (n * DD + y)], acc);
  }
}

// ---------------- K6: edge blocks (ij and ji together), 1 edge/block ----------------
__global__ __launch_bounds__(256) void k_edge_block(
    const float* __restrict__ nh, const float* __restrict__ emsg,
    const int* __restrict__ src, const int* __restrict__ dst,
    const int* __restrict__ etype, const float* __restrict__ Wproj,
    const float* __restrict__ Wedge, const float* __restrict__ cob,
    float* __restrict__ M) {
  int e = blockIdx.x, t = threadIdx.x;
  int s = src[e], d = dst[e], p = etype[e];
  __shared__ float xin[384];  // [msg(128) | nh_s(128) | nh_d(128)]
  __shared__ float hpij[256], hpji[256];
  __shared__ float h_ij[KDIM], h_ji[KDIM];
  __shared__ float irr_ij[I_EDGE], irr_ji[I_EDGE];
  __shared__ float blk_ij[I_EDGE], blk_ji[I_EDGE];

  if (t < 128) {
    xin[t] = emsg[e * HH + t];
    xin[256 + t] = nh[d * FF + t];
  } else {
    xin[t] = nh[s * FF + (t - 128)];
  }
  __syncthreads();

  // h = x @ W_proj  (384 x 64), split input range over 4 segments of 96
  {
    int k = t & 63, seg = t >> 6;
    float aij = 0.f, aji = 0.f;
    const float* Wp = Wproj + k;
    int i0 = seg * 96;
    for (int i = i0; i < i0 + 96; ++i) {
      float w = Wp[i * KDIM];
      int iswap = (i < 128) ? i : ((i < 256) ? i + 128 : i - 128);
      aij += xin[i] * w;
      aji += xin[iswap] * w;
    }
    hpij[t] = aij; hpji[t] = aji;
  }
  __syncthreads();
  if (t < KDIM) {
    h_ij[t] = hpij[t] + hpij[t + 64] + hpij[t + 128] + hpij[t + 192];
    h_ji[t] = hpji[t] + hpji[t + 64] + hpji[t + 128] + hpji[t + 192];
  }
  __syncthreads();

  // irr = h @ W_edge[p]  (64 x 169), same weights for ij/ji
  if (t < I_EDGE) {
    float aij = 0.f, aji = 0.f;
    const float* W = Wedge + p * KDIM * I_EDGE + t;
#pragma unroll 4
    for (int k = 0; k < KDIM; ++k) {
      float w = W[k * I_EDGE];
      aij += h_ij[k] * w;
      aji += h_ji[k] * w;
    }
    irr_ij[t] = aij; irr_ji[t] = aji;
  }
  __syncthreads();

  // blk = irr @ cob_edge[p]  (169 x 169)
  if (t < I_EDGE) {
    float aij = 0.f, aji = 0.f;
    const float* C = cob + p * I_EDGE * I_EDGE + t;
    for (int i = 0; i < I_EDGE; ++i) {
      float c = C[i * I_EDGE];
      aij += irr_ij[i] * c;
      aji += irr_ji[i] * c;
    }
    blk_ij[t] = aij; blk_ji[t] = aji;
  }
  __syncthreads();

  if (t < I_EDGE) {
    int x = t / DD, y = t % DD;
    float eb = 0.5f * (blk_ij[t] + blk_ji[y * DD + x]);  // 0.5*(ij + ji^T)
    atomicAdd(&M[(size_t)(s * DD + x) * MROW + (d * DD + y)], eb);
    // M[cs, rs] += eb^T  ==  M[d*13+y, s*13+x] += eb[x, y]
    atomicAdd(&M[(size_t)(d * DD + y) * MROW + (s * DD + x)], eb);
  }
}

extern "C" void kernel_launch(void* const* d_in, const int* in_sizes, int n_in,
                              void* d_out, int out_size, void* d_ws, size_t ws_size,
                              hipStream_t stream) {
  const float* node_feats = (const float*)d_in[0];
  const float* node_attrs = (const float*)d_in[1];
  const float* edge_feats = (const float*)d_in[2];
  const float* edge_attrs = (const float*)d_in[3];
  const int*   edge_index = (const int*)d_in[4];
  const int*   node_types = (const int*)d_in[5];
  const int*   edge_types = (const int*)d_in[6];
  const float* W_msg  = (const float*)d_in[7];
  const float* W_attr = (const float*)d_in[8];
  const float* W_em   = (const float*)d_in[9];
  const float* W_proj = (const float*)d_in[10];
  const float* W_node = (const float*)d_in[11];
  const float* W_edge = (const float*)d_in[12];
  const float* cob_node = (const float*)d_in[13];
  const float* cob_edge = (const float*)d_in[14];

  float* M  = (float*)d_out;
  float* ws = (float*)d_ws;
  float* m_buf = ws;              // N*F = 128000
  float* agg   = ws + 128000;     // N*F
  float* nh    = ws + 256000;     // N*F
  float* emsg  = ws + 384000;     // E*H = 2,560,000  (total ~11.8 MB)

  const int* src = edge_index;        // edge_index[0]
  const int* dst = edge_index + EE;   // edge_index[1]

  hipMemsetAsync(d_out, 0, (size_t)out_size * sizeof(float), stream);

  k_node_msg <<<NN, 128, 0, stream>>>(node_feats, W_msg, m_buf, agg);
  k_scatter  <<<(EE * FF) / 256, 256, 0, stream>>>(m_buf, src, dst, agg);
  k_node_h   <<<NN, 128, 0, stream>>>(node_feats, agg, node_attrs, W_attr, nh);
  k_edge_msg <<<EE / EPB, 128, 0, stream>>>(nh, edge_feats, edge_attrs, src, dst, W_em, emsg);
  k_node_block<<<NN, 256, 0, stream>>>(nh, node_types, W_node, cob_node, M);
  k_edge_block<<<EE, 256, 0, stream>>>(nh, emsg, src, dst, edge_types,
                                       W_proj, W_edge, cob_edge, M);
}